// Round 1
// baseline (465.249 us; speedup 1.0000x reference)
//
#include <hip/hip_runtime.h>
#include <cstdint>

#define T_STEPS 32
#define NB 64
#define STATE 64
#define HID 128
#define ACT 32
#define CDIM 96
#define G3 (3*HID)   // 384

typedef __attribute__((ext_vector_type(8))) short short8;
typedef __attribute__((ext_vector_type(4))) float f32x4;

__device__ __forceinline__ float bf2f_lo(unsigned int dw){ unsigned int u = dw << 16; return __builtin_bit_cast(float, u); }
__device__ __forceinline__ float bf2f_hi(unsigned int dw){ unsigned int u = dw & 0xFFFF0000u; return __builtin_bit_cast(float, u); }
__device__ __forceinline__ unsigned short f2bf(float f){
  unsigned int u = __builtin_bit_cast(unsigned int, f);
  u = u + 0x7FFFu + ((u >> 16) & 1u);
  return (unsigned short)(u >> 16);
}
__device__ __forceinline__ float sigmoidf_(float x){ return 1.0f/(1.0f + __expf(-x)); }
__device__ __forceinline__ float tanhf_(float x){ float e = __expf(2.0f*x); return (e-1.0f)/(e+1.0f); }

// out[t][n][r] = bias[r] + sum_k w[r][k] * in[t][n][k]   (r = 0..383)
template<int K>
__global__ void k_giproj(const float* __restrict__ in, const float* __restrict__ w,
                         const float* __restrict__ bias, float* __restrict__ out){
  int tid = blockIdx.x*256 + threadIdx.x;
  if (tid >= T_STEPS*NB*G3) return;
  int r  = tid % G3;
  int tn = tid / G3;
  const float4* wr = (const float4*)(w + r*K);
  const float4* xr = (const float4*)(in + tn*K);
  float acc = bias[r];
  #pragma unroll
  for (int i = 0; i < K/4; i++){
    float4 u = xr[i], v = wr[i];
    acc += u.x*v.x + u.y*v.y + u.z*v.z + u.w*v.w;
  }
  out[tid] = acc;
}

// One block per sample. Recurrent weights bf16-packed in LDS (384 rows, pitch 66 dwords).
// gi already contains x@wih.T + bih.   gh kept separate (n-gate needs r*gh_n).
__global__ __launch_bounds__(384) void k_gru(const float* __restrict__ gi, const float* __restrict__ whh,
                                             const float* __restrict__ bhh, float* __restrict__ hout){
  __shared__ unsigned int wl[G3*66];
  __shared__ __align__(16) float hl[HID];
  __shared__ float ghl[G3];
  int n = blockIdx.x;
  int r = threadIdx.x;
  for (int d = r; d < G3*64; d += 384){
    int row = d >> 6, c2 = d & 63;
    float2 f = *(const float2*)(whh + row*HID + c2*2);
    wl[row*66 + c2] = (unsigned int)f2bf(f.x) | ((unsigned int)f2bf(f.y) << 16);
  }
  if (r < HID) hl[r] = 0.0f;
  float brow = bhh[r];
  __syncthreads();
  for (int t = 0; t < T_STEPS; t++){
    float acc = brow;
    const unsigned int* wr = &wl[r*66];
    #pragma unroll 8
    for (int kk = 0; kk < 32; kk++){
      unsigned int d0 = wr[kk*2], d1 = wr[kk*2+1];
      float4 h4 = *(const float4*)&hl[kk*4];         // same addr across lanes -> broadcast
      acc += bf2f_lo(d0)*h4.x + bf2f_hi(d0)*h4.y + bf2f_lo(d1)*h4.z + bf2f_hi(d1)*h4.w;
    }
    ghl[r] = acc;
    __syncthreads();
    if (r < HID){
      const float* g = gi + (t*NB + n)*G3;
      float rg = sigmoidf_(g[r]       + ghl[r]);
      float z  = sigmoidf_(g[r+HID]   + ghl[r+HID]);
      float nn = tanhf_   (g[r+2*HID] + rg*ghl[r+2*HID]);
      float hn = (1.0f - z)*nn + z*hl[r];
      hl[r] = hn;
      hout[(t*NB + n)*HID + r] = hn;
    }
    __syncthreads();
  }
}

// fc1[t,n,j] = relu(b1[j] + sum_{k<128} w1[j,k] p[t,n,k] + sum_{k<32} w1[j,128+k] a[t,n,k])
__global__ void k_fc1(const float* __restrict__ p, const float* __restrict__ a,
                      const float* __restrict__ w1, const float* __restrict__ b1,
                      float* __restrict__ fc1f, unsigned short* __restrict__ fc1h){
  int tid = blockIdx.x*256 + threadIdx.x;
  if (tid >= T_STEPS*NB*HID) return;
  int j  = tid & (HID-1);
  int tn = tid >> 7;
  const float4* wr = (const float4*)(w1 + j*(HID+ACT));
  const float4* pr = (const float4*)(p + tn*HID);
  const float4* ar = (const float4*)(a + tn*ACT);
  float acc = b1[j];
  #pragma unroll
  for (int i = 0; i < HID/4; i++){ float4 u = pr[i], v = wr[i]; acc += u.x*v.x+u.y*v.y+u.z*v.z+u.w*v.w; }
  const float4* wr2 = wr + HID/4;
  #pragma unroll
  for (int i = 0; i < ACT/4; i++){ float4 u = ar[i], v = wr2[i]; acc += u.x*v.x+u.y*v.y+u.z*v.z+u.w*v.w; }
  acc = fmaxf(acc, 0.0f);
  fc1f[tid] = acc;
  fc1h[tid] = f2bf(acc);
}

// Tm[k][b][c] -> tmh[b][c][k] (bf16), via LDS transpose. One block per b.
__global__ void k_tmprep(const float* __restrict__ Tm, unsigned short* __restrict__ tmh){
  __shared__ unsigned short tl[CDIM*132];
  int b = blockIdx.x;
  for (int e = threadIdx.x; e < HID*CDIM; e += 256){
    int k = e / CDIM, c = e - k*CDIM;
    tl[c*132 + k] = f2bf(Tm[k*(HID*CDIM) + b*CDIM + c]);
  }
  __syncthreads();
  for (int e = threadIdx.x; e < CDIM*HID; e += 256){
    int c = e >> 7, k = e & 127;
    tmh[b*(CDIM*HID) + e] = tl[c*132 + k];
  }
}

// One block per (b, t): M = fc1_t @ Tm[:,b,:]  (64x96, bf16 MFMA), then pairwise L1 + exp + col-sum.
__global__ __launch_bounds__(256) void k_disc(const unsigned short* __restrict__ fc1h,
                                              const unsigned short* __restrict__ tmh,
                                              float* __restrict__ O){
  __shared__ __align__(16) unsigned short Al[64*136];   // fc1_t rows, pitch 272B
  __shared__ __align__(16) unsigned short Bl[96*136];   // Tm[b] as [c][k], pitch 272B
  __shared__ __align__(16) float Ml[64*96];             // M, chunk-XOR-swizzled
  __shared__ float ps[64*17];
  int b = blockIdx.x, t = blockIdx.y;
  int tid = threadIdx.x;
  const uint4* Ag = (const uint4*)(fc1h + t*(NB*HID));
  for (int ch = tid; ch < 64*16; ch += 256){
    int row = ch >> 4, c16 = ch & 15;
    *(uint4*)&Al[row*136 + c16*8] = Ag[ch];
  }
  const uint4* Bg = (const uint4*)(tmh + b*(CDIM*HID));
  for (int ch = tid; ch < 96*16; ch += 256){
    int row = ch >> 4, c16 = ch & 15;
    *(uint4*)&Bl[row*136 + c16*8] = Bg[ch];
  }
  __syncthreads();
  {
    int wave = tid >> 6, lane = tid & 63, m = lane & 15, quad = lane >> 4;
    f32x4 acc[6];
    #pragma unroll
    for (int i = 0; i < 6; i++) acc[i] = (f32x4)(0.0f);
    #pragma unroll
    for (int kk = 0; kk < 4; kk++){
      short8 av = *(const short8*)&Al[(wave*16 + m)*136 + kk*32 + quad*8];
      #pragma unroll
      for (int nt = 0; nt < 6; nt++){
        short8 bv = *(const short8*)&Bl[(nt*16 + m)*136 + kk*32 + quad*8];
        acc[nt] = __builtin_amdgcn_mfma_f32_16x16x32_bf16(av, bv, acc[nt], 0, 0, 0);
      }
    }
    // D: col = lane&15 (c within tile), row = quad*4 + reg (sample within tile)
    #pragma unroll
    for (int nt = 0; nt < 6; nt++){
      #pragma unroll
      for (int rr = 0; rr < 4; rr++){
        int row = wave*16 + quad*4 + rr;
        int c = nt*16 + m;
        int cc = c >> 2;
        int pcc = cc ^ ((row >> 2) & 7);
        Ml[row*96 + pcc*4 + (c & 3)] = acc[nt][rr];
      }
    }
  }
  __syncthreads();
  // pairwise: thread (ti,tj) owns 4x4 pair tile
  int ti = tid >> 4, tj = tid & 15;
  float pa[4][4];
  #pragma unroll
  for (int i = 0; i < 4; i++)
    #pragma unroll
    for (int j = 0; j < 4; j++) pa[i][j] = 0.0f;
  for (int cc = 0; cc < 24; cc++){
    float4 mi[4], mj[4];
    int pi = (cc ^ (ti & 7))*4, pj = (cc ^ (tj & 7))*4;
    #pragma unroll
    for (int s = 0; s < 4; s++){
      mi[s] = *(const float4*)&Ml[(ti*4+s)*96 + pi];
      mj[s] = *(const float4*)&Ml[(tj*4+s)*96 + pj];
    }
    #pragma unroll
    for (int i2 = 0; i2 < 4; i2++)
      #pragma unroll
      for (int j2 = 0; j2 < 4; j2++){
        pa[i2][j2] += fabsf(mi[i2].x - mj[j2].x) + fabsf(mi[i2].y - mj[j2].y)
                    + fabsf(mi[i2].z - mj[j2].z) + fabsf(mi[i2].w - mj[j2].w);
      }
  }
  #pragma unroll
  for (int j2 = 0; j2 < 4; j2++){
    float s = 0.0f;
    #pragma unroll
    for (int i2 = 0; i2 < 4; i2++) s += __expf(-pa[i2][j2]);
    ps[(tj*4 + j2)*17 + ti] = s;
  }
  __syncthreads();
  if (tid < NB){
    float s = 0.0f;
    #pragma unroll
    for (int i = 0; i < 16; i++) s += ps[tid*17 + i];
    O[t*(NB*HID) + b*NB + tid] = (s - 1.0f) * (1.0f/63.0f);   // diag exp(0)=1 removed
  }
}

// prob[t,n] = sigmoid(b2 + fc1[t,n,:]·w2[:128] + O[t,:,n]·w2[128:])
__global__ __launch_bounds__(256) void k_final(const float* __restrict__ fc1f, const float* __restrict__ O,
                                               const float* __restrict__ w2, const float* __restrict__ b2,
                                               float* __restrict__ out){
  __shared__ float ol[NB*HID];      // [b][n]
  __shared__ float fl[NB*130];      // padded fc1 rows
  __shared__ float wl[2*HID + 2];
  int t = blockIdx.x, tid = threadIdx.x;
  for (int i = tid; i < NB*HID; i += 256) ol[i] = O[t*NB*HID + i];
  for (int i = tid; i < NB*HID; i += 256){ int n = i >> 7, h = i & 127; fl[n*130 + h] = fc1f[t*NB*HID + i]; }
  if (tid < 2*HID) wl[tid] = w2[tid];
  if (tid == 0) wl[2*HID] = b2[0];
  __syncthreads();
  if (tid < NB){
    float acc = wl[2*HID];
    #pragma unroll 8
    for (int h = 0; h < HID; h++) acc += fl[tid*130 + h]*wl[h];
    #pragma unroll 8
    for (int b = 0; b < HID; b++) acc += ol[b*NB + tid]*wl[HID + b];
    out[t*NB + tid] = sigmoidf_(acc);
  }
}

extern "C" void kernel_launch(void* const* d_in, const int* in_sizes, int n_in,
                              void* d_out, int out_size, void* d_ws, size_t ws_size,
                              hipStream_t stream){
  const float* x    = (const float*)d_in[0];
  const float* a    = (const float*)d_in[1];
  const float* wih0 = (const float*)d_in[2];
  const float* whh0 = (const float*)d_in[3];
  const float* bih0 = (const float*)d_in[4];
  const float* bhh0 = (const float*)d_in[5];
  const float* wih1 = (const float*)d_in[6];
  const float* whh1 = (const float*)d_in[7];
  const float* bih1 = (const float*)d_in[8];
  const float* bhh1 = (const float*)d_in[9];
  const float* w1   = (const float*)d_in[10];
  const float* b1   = (const float*)d_in[11];
  const float* w2   = (const float*)d_in[12];
  const float* b2   = (const float*)d_in[13];
  const float* Tm   = (const float*)d_in[14];
  float* ws = (float*)d_ws;
  float* gi0  = ws;
  float* gi1  = ws + 786432;
  float* hs0  = ws + 1572864;
  float* pws  = ws + 1835008;
  float* fc1f = ws + 2097152;
  float* Ows  = ws + 2359296;
  unsigned short* fc1h = (unsigned short*)(ws + 2621440);
  unsigned short* tmh  = (unsigned short*)(ws + 2752512);
  float* out = (float*)d_out;

  k_giproj<STATE><<<dim3(3072), dim3(256), 0, stream>>>(x, wih0, bih0, gi0);
  k_tmprep<<<dim3(HID), dim3(256), 0, stream>>>(Tm, tmh);
  k_gru<<<dim3(NB), dim3(384), 0, stream>>>(gi0, whh0, bhh0, hs0);
  k_giproj<HID><<<dim3(3072), dim3(256), 0, stream>>>(hs0, wih1, bih1, gi1);
  k_gru<<<dim3(NB), dim3(384), 0, stream>>>(gi1, whh1, bhh1, pws);
  k_fc1<<<dim3(1024), dim3(256), 0, stream>>>(pws, a, w1, b1, fc1f, fc1h);
  k_disc<<<dim3(HID, T_STEPS), dim3(256), 0, stream>>>(fc1h, tmh, Ows);
  k_final<<<dim3(T_STEPS), dim3(256), 0, stream>>>(fc1f, Ows, w2, b2, out);
}

// Round 2
// 367.818 us; speedup vs baseline: 1.2649x; 1.2649x over previous
//
#include <hip/hip_runtime.h>
#include <hip/hip_fp16.h>
#include <cstdint>

#define T_STEPS 32
#define NB 64
#define STATE 64
#define HID 128
#define ACT 32
#define CDIM 96
#define G3 (3*HID)   // 384

typedef __attribute__((ext_vector_type(8))) short short8;
typedef __attribute__((ext_vector_type(4))) float f32x4;

__device__ __forceinline__ unsigned short f2bf(float f){
  unsigned int u = __builtin_bit_cast(unsigned int, f);
  u = u + 0x7FFFu + ((u >> 16) & 1u);
  return (unsigned short)(u >> 16);
}
__device__ __forceinline__ float sigmoidf_(float x){ return 1.0f/(1.0f + __expf(-x)); }
__device__ __forceinline__ float tanhf_(float x){ float e = __expf(2.0f*x); return (e-1.0f)/(e+1.0f); }

__device__ __forceinline__ __half2 l1acc(__half2 acc, unsigned int ua, unsigned int ub){
  __half2 a = __builtin_bit_cast(__half2, ua);
  __half2 b = __builtin_bit_cast(__half2, ub);
  return __hadd2(acc, __habs2(__hsub2(a, b)));
}

// ---------------- prep: Tm transpose->bf16  +  weight transposes ----------------
__global__ void k_prep(const float* __restrict__ Tm, unsigned short* __restrict__ tmh,
                       const float* __restrict__ wih0, const float* __restrict__ whh0,
                       const float* __restrict__ wih1, const float* __restrict__ whh1,
                       const float* __restrict__ w1,
                       float* __restrict__ wih0T, float* __restrict__ whh0T,
                       float* __restrict__ wih1T, float* __restrict__ whh1T,
                       float* __restrict__ wfcT){
  __shared__ unsigned short tl[CDIM*132];
  if (blockIdx.x < 128){
    int b = blockIdx.x;
    for (int e = threadIdx.x; e < HID*CDIM; e += 256){
      int k = e / CDIM, c = e - k*CDIM;
      tl[c*132 + k] = f2bf(Tm[k*(HID*CDIM) + b*CDIM + c]);
    }
    __syncthreads();
    for (int e = threadIdx.x; e < CDIM*HID; e += 256){
      int c = e >> 7, k = e & 127;
      tmh[b*(CDIM*HID) + e] = tl[c*132 + k];
    }
  } else {
    int mb = blockIdx.x - 128;   // 0..23
    const float* srcs[5] = {wih0, whh0, wih1, whh1, w1};
    float*       dsts[5] = {wih0T, whh0T, wih1T, whh1T, wfcT};
    const int Rs[5] = {384,384,384,384,128};
    const int Ks[5] = {64,128,128,128,160};
    for (int mm = 0; mm < 5; mm++){
      const float* s = srcs[mm]; float* d = dsts[mm];
      int R = Rs[mm], K = Ks[mm], tot = R*K;
      for (int e = mb*256 + (int)threadIdx.x; e < tot; e += 24*256){
        int r = e / K, k = e - r*K;
        d[k*R + r] = s[e];
      }
    }
  }
}

// ---------------- projection GEMM: out[tn][r] = bias[r] + concat(in1,in2)[tn] . wT[:,r] ----------------
// lane = r, weights in registers (K split across wave pairs), x broadcast from LDS.
template<int K1, int K2, int R, bool FUSE>
__global__ __launch_bounds__(256) void k_proj(const float* __restrict__ in1, const float* __restrict__ in2,
                                              const float* __restrict__ wT, const float* __restrict__ bias,
                                              float* __restrict__ outf, unsigned short* __restrict__ outh){
  constexpr int K = K1 + K2;
  constexpr int KH = K/2;
  __shared__ float xs[32*K];
  __shared__ float part[32*128];
  int tid = threadIdx.x;
  int tn0 = blockIdx.x*32;
  int rb  = blockIdx.y*128;
  int w = tid >> 6, lane = tid & 63;
  int rt = w >> 1, kh = w & 1;
  int r = rb + rt*64 + lane;
  float wreg[KH];
  #pragma unroll
  for (int i = 0; i < KH; i++) wreg[i] = wT[(kh*KH + i)*R + r];
  const float4* i1 = (const float4*)(in1 + tn0*K1);
  for (int g = tid; g < 32*(K1/4); g += 256){
    int tnl = g / (K1/4), k4 = g - tnl*(K1/4);
    *(float4*)&xs[tnl*K + k4*4] = i1[g];
  }
  if (K2 > 0){
    const float4* i2 = (const float4*)(in2 + tn0*K2);
    for (int g = tid; g < 32*(K2/4); g += 256){
      int tnl = g / (K2/4), k4 = g - tnl*(K2/4);
      *(float4*)&xs[tnl*K + K1 + k4*4] = i2[g];
    }
  }
  __syncthreads();
  float acc[32];
  #pragma unroll
  for (int i = 0; i < 32; i++) acc[i] = 0.0f;
  #pragma unroll
  for (int kc = 0; kc < KH/4; kc++){
    #pragma unroll
    for (int tnl = 0; tnl < 32; tnl++){
      float4 xv = *(const float4*)&xs[tnl*K + kh*KH + kc*4];
      acc[tnl] += wreg[kc*4]*xv.x + wreg[kc*4+1]*xv.y + wreg[kc*4+2]*xv.z + wreg[kc*4+3]*xv.w;
    }
  }
  if (kh == 1){
    #pragma unroll
    for (int tnl = 0; tnl < 32; tnl++) part[tnl*128 + rt*64 + lane] = acc[tnl];
  }
  __syncthreads();
  if (kh == 0){
    float bv = bias[r];
    #pragma unroll
    for (int tnl = 0; tnl < 32; tnl++){
      float v = acc[tnl] + part[tnl*128 + rt*64 + lane] + bv;
      if (FUSE) v = fmaxf(v, 0.0f);
      outf[(tn0+tnl)*R + r] = v;
      if (FUSE) outh[(tn0+tnl)*R + r] = f2bf(v);
    }
  }
}

// ---------------- GRU recurrence: one block per sample, recurrent weights in VGPRs ----------------
// thread = (r = tid>>1, khalf = tid&1); 64 fp32 weights each; gi pre-projected (x@wih.T+bih).
__global__ __launch_bounds__(768) void k_gru(const float* __restrict__ gi, const float* __restrict__ whhT,
                                             const float* __restrict__ bhh, float* __restrict__ hout){
  __shared__ __align__(16) float hl[HID];
  __shared__ float ghl[G3];
  int n = blockIdx.x, tid = threadIdx.x;
  int r = tid >> 1, kh = tid & 1;
  float wreg[64];
  #pragma unroll
  for (int i = 0; i < 64; i++) wreg[i] = whhT[(kh*64 + i)*G3 + r];
  float bias = (kh == 0) ? bhh[r] : 0.0f;
  if (tid < HID) hl[tid] = 0.0f;
  float g_r = 0.0f, g_z = 0.0f, g_n = 0.0f;
  if (tid < HID){
    const float* g0 = gi + n*G3 + tid;
    g_r = g0[0]; g_z = g0[HID]; g_n = g0[2*HID];
  }
  __syncthreads();
  for (int t = 0; t < T_STEPS; t++){
    float acc = bias;
    #pragma unroll
    for (int i16 = 0; i16 < 16; i16++){
      float4 h4 = *(const float4*)&hl[kh*64 + i16*4];   // broadcast read
      acc += wreg[i16*4]*h4.x + wreg[i16*4+1]*h4.y + wreg[i16*4+2]*h4.z + wreg[i16*4+3]*h4.w;
    }
    float asum = acc + __shfl_xor(acc, 1);
    if (kh == 0) ghl[r] = asum;
    __syncthreads();
    if (tid < HID){
      float cr = g_r, cz = g_z, cn = g_n;
      int tnext = (t+1 < T_STEPS) ? t+1 : t;           // prefetch next timestep's gi
      const float* gp = gi + (tnext*NB + n)*G3 + tid;
      g_r = gp[0]; g_z = gp[HID]; g_n = gp[2*HID];
      float rg = sigmoidf_(cr + ghl[tid]);
      float z  = sigmoidf_(cz + ghl[tid+HID]);
      float nn = tanhf_   (cn + rg*ghl[tid+2*HID]);
      float hn = (1.0f - z)*nn + z*hl[tid];
      hl[tid] = hn;
      hout[(t*NB + n)*HID + tid] = hn;
    }
    __syncthreads();
  }
}

// ---------------- minibatch discrimination: one block per (b,t) ----------------
// MFMA (A from global, B staged+swizzled) -> M fp16 in LDS -> symmetric fp16 pairwise
// via tile-level round-robin tournament -> per-player sums via LDS atomics.
__global__ __launch_bounds__(256) void k_disc(const unsigned short* __restrict__ fc1h,
                                              const unsigned short* __restrict__ tmh,
                                              float* __restrict__ O){
  __shared__ __align__(16) unsigned short Bl[96*128];  // [c][k], chunk-XOR swizzled
  __shared__ __align__(16) __half Mh[64*104];          // row=(p&3)*16+(p>>2), pitch 104 halves
  __shared__ float col[64];
  int b = blockIdx.x, t = blockIdx.y;
  int tid = threadIdx.x;
  // stage B (swizzle 16B chunk index by row&7)
  const uint4* Bg = (const uint4*)(tmh + b*(CDIM*HID));
  for (int g = tid; g < 96*16/2*2; g += 256){ }
  for (int g = tid; g < 1536; g += 256){
    int row = g >> 4, c = g & 15;
    *(uint4*)&Bl[row*128 + ((c ^ (row & 7))*8)] = Bg[g];
  }
  if (tid < 64) col[tid] = 0.0f;
  int wave = tid >> 6, lane = tid & 63, m = lane & 15, quad = lane >> 4;
  const uint4* Ag = (const uint4*)(fc1h + (t*NB + wave*16 + m)*HID);
  uint4 a4[4];
  #pragma unroll
  for (int kk = 0; kk < 4; kk++) a4[kk] = Ag[kk*4 + quad];
  __syncthreads();
  {
    f32x4 acc[6];
    #pragma unroll
    for (int i = 0; i < 6; i++) acc[i] = (f32x4)(0.0f);
    #pragma unroll
    for (int kk = 0; kk < 4; kk++){
      short8 av = __builtin_bit_cast(short8, a4[kk]);
      int c = kk*4 + quad;
      #pragma unroll
      for (int nt = 0; nt < 6; nt++){
        short8 bv = *(const short8*)&Bl[(nt*16 + m)*128 + ((c ^ (m & 7))*8)];
        acc[nt] = __builtin_amdgcn_mfma_f32_16x16x32_bf16(av, bv, acc[nt], 0, 0, 0);
      }
    }
    // D: col = nt*16 + (lane&15), row = wave*16 + quad*4 + rr  -> Mh row (rr*16 + wave*4 + quad)
    #pragma unroll
    for (int nt = 0; nt < 6; nt++){
      #pragma unroll
      for (int rr = 0; rr < 4; rr++){
        Mh[(rr*16 + wave*4 + quad)*104 + nt*16 + m] = __float2half(acc[nt][rr]);
      }
    }
  }
  __syncthreads();
  // pairwise over unordered pairs: 120 off-diag 4x4 tile-pairs x 2 c-halves (tid 0..239),
  // 96 diag pairs ride on tid 0..191.
  int chalf = tid & 1;
  int ch0 = chalf*6;
  const uint4* M4 = (const uint4*)Mh;   // 13 uint4 per row
  if (tid < 240){
    int tp = tid >> 1;
    int rnd = tp >> 3, slot = tp & 7;
    int ta, tb;
    if (slot == 0){ ta = 15; tb = rnd; }
    else {
      ta = rnd + slot;      if (ta >= 15) ta -= 15;
      tb = rnd + 15 - slot; if (tb >= 15) tb -= 15;
    }
    bool dact = (tid < 192);
    int td = 0, di = 0, dj = 0;
    if (dact){
      int dp = tid >> 1;            // 0..95
      td = (dp*171) >> 10;          // dp/6
      int pi = dp - td*6;
      di = (pi < 3) ? 0 : ((pi < 5) ? 1 : 2);
      dj = (pi < 3) ? (pi + 1) : ((pi < 5) ? (pi - 2) : 3);
    }
    __half2 pacc[16];
    #pragma unroll
    for (int p = 0; p < 16; p++) pacc[p] = __float2half2_rn(0.0f);
    __half2 dacc = __float2half2_rn(0.0f);
    for (int c = 0; c < 6; c++){
      int ch = ch0 + c;
      uint4 av[4], bv[4];
      #pragma unroll
      for (int s = 0; s < 4; s++){
        av[s] = M4[(s*16 + ta)*13 + ch];
        bv[s] = M4[(s*16 + tb)*13 + ch];
      }
      #pragma unroll
      for (int i = 0; i < 4; i++){
        #pragma unroll
        for (int j = 0; j < 4; j++){
          __half2 a0 = pacc[i*4+j];
          a0 = l1acc(a0, av[i].x, bv[j].x);
          a0 = l1acc(a0, av[i].y, bv[j].y);
          a0 = l1acc(a0, av[i].z, bv[j].z);
          a0 = l1acc(a0, av[i].w, bv[j].w);
          pacc[i*4+j] = a0;
        }
      }
      if (dact){
        uint4 u = M4[(di*16 + td)*13 + ch];
        uint4 v = M4[(dj*16 + td)*13 + ch];
        dacc = l1acc(dacc, u.x, v.x);
        dacc = l1acc(dacc, u.y, v.y);
        dacc = l1acc(dacc, u.z, v.z);
        dacc = l1acc(dacc, u.w, v.w);
      }
    }
    float tot[16];
    #pragma unroll
    for (int p = 0; p < 16; p++){
      float nf = __low2float(pacc[p]) + __high2float(pacc[p]);
      tot[p] = nf + __shfl_xor(nf, 1);
    }
    float ndg = __low2float(dacc) + __high2float(dacc);
    float dtot = ndg + __shfl_xor(ndg, 1);
    int pbase = chalf*8;
    #pragma unroll
    for (int q = 0; q < 8; q++){
      int p = pbase + q;
      float e = __expf(-tot[p]);
      atomicAdd(&col[ta*4 + (p >> 2)], e);
      atomicAdd(&col[tb*4 + (p & 3)], e);
    }
    if (dact && chalf == 0){
      float e = __expf(-dtot);
      atomicAdd(&col[td*4 + di], e);
      atomicAdd(&col[td*4 + dj], e);
    }
  }
  __syncthreads();
  if (tid < NB) O[(t*HID + b)*NB + tid] = col[tid]*(1.0f/63.0f);
}

// ---------------- final: prob = sigmoid(b2 + fc1.w2[:H] + O(:,n).w2[H:]) ----------------
__global__ __launch_bounds__(256) void k_final(const float* __restrict__ fc1f, const float* __restrict__ O,
                                               const float* __restrict__ w2, const float* __restrict__ b2,
                                               float* __restrict__ out){
  __shared__ float ol[NB*HID];      // [b][n]
  __shared__ float fl[NB*130];
  __shared__ float wl[2*HID + 2];
  int t = blockIdx.x, tid = threadIdx.x;
  for (int i = tid; i < NB*HID; i += 256) ol[i] = O[t*NB*HID + i];
  for (int i = tid; i < NB*HID; i += 256){ int n = i >> 7, h = i & 127; fl[n*130 + h] = fc1f[t*NB*HID + i]; }
  if (tid < 2*HID) wl[tid] = w2[tid];
  if (tid == 0) wl[2*HID] = b2[0];
  __syncthreads();
  if (tid < NB){
    float acc = wl[2*HID];
    #pragma unroll 8
    for (int h = 0; h < HID; h++) acc += fl[tid*130 + h]*wl[h];
    #pragma unroll 8
    for (int b = 0; b < HID; b++) acc += ol[b*NB + tid]*wl[HID + b];
    out[t*NB + tid] = sigmoidf_(acc);
  }
}

extern "C" void kernel_launch(void* const* d_in, const int* in_sizes, int n_in,
                              void* d_out, int out_size, void* d_ws, size_t ws_size,
                              hipStream_t stream){
  const float* x    = (const float*)d_in[0];
  const float* a    = (const float*)d_in[1];
  const float* wih0 = (const float*)d_in[2];
  const float* whh0 = (const float*)d_in[3];
  const float* bih0 = (const float*)d_in[4];
  const float* bhh0 = (const float*)d_in[5];
  const float* wih1 = (const float*)d_in[6];
  const float* whh1 = (const float*)d_in[7];
  const float* bih1 = (const float*)d_in[8];
  const float* bhh1 = (const float*)d_in[9];
  const float* w1   = (const float*)d_in[10];
  const float* b1   = (const float*)d_in[11];
  const float* w2   = (const float*)d_in[12];
  const float* b2   = (const float*)d_in[13];
  const float* Tm   = (const float*)d_in[14];
  float* ws = (float*)d_ws;
  float* gi    = ws;                    // 786432 (shared by layer0/layer1 gi)
  float* hs0   = ws + 786432;           // 262144
  float* hs1   = ws + 1048576;          // 262144
  float* fc1f  = ws + 1310720;          // 262144
  float* Ows   = ws + 1572864;          // 262144
  unsigned short* fc1h = (unsigned short*)(ws + 1835008);  // 131072 floats
  unsigned short* tmh  = (unsigned short*)(ws + 1966080);  // 786432 floats
  float* wih0T = ws + 2752512;          // 24576
  float* whh0T = ws + 2777088;          // 49152
  float* wih1T = ws + 2826240;          // 49152
  float* whh1T = ws + 2875392;          // 49152
  float* wfcT  = ws + 2924544;          // 20480
  float* out = (float*)d_out;

  k_prep<<<dim3(152), dim3(256), 0, stream>>>(Tm, tmh, wih0, whh0, wih1, whh1, w1,
                                              wih0T, whh0T, wih1T, whh1T, wfcT);
  k_proj<64, 0, 384, false><<<dim3(64, 3), dim3(256), 0, stream>>>(x, nullptr, wih0T, bih0, gi, nullptr);
  k_gru<<<dim3(NB), dim3(768), 0, stream>>>(gi, whh0T, bhh0, hs0);
  k_proj<128, 0, 384, false><<<dim3(64, 3), dim3(256), 0, stream>>>(hs0, nullptr, wih1T, bih1, gi, nullptr);
  k_gru<<<dim3(NB), dim3(768), 0, stream>>>(gi, whh1T, bhh1, hs1);
  k_proj<128, 32, 128, true><<<dim3(64, 1), dim3(256), 0, stream>>>(hs1, a, wfcT, b1, fc1f, fc1h);
  k_disc<<<dim3(HID, T_STEPS), dim3(256), 0, stream>>>(fc1h, tmh, Ows);
  k_final<<<dim3(T_STEPS), dim3(256), 0, stream>>>(fc1f, Ows, w2, b2, out);
}

// Round 3
// 291.049 us; speedup vs baseline: 1.5985x; 1.2638x over previous
//
#include <hip/hip_runtime.h>
#include <hip/hip_fp16.h>
#include <cstdint>

#define T_STEPS 32
#define NB 64
#define STATE 64
#define HID 128
#define ACT 32
#define CDIM 96
#define G3 (3*HID)   // 384

typedef __attribute__((ext_vector_type(8))) short short8;
typedef __attribute__((ext_vector_type(4))) float f32x4;
typedef _Float16 h2v __attribute__((ext_vector_type(2)));

__device__ __forceinline__ unsigned short f2bf(float f){
  unsigned int u = __builtin_bit_cast(unsigned int, f);
  u = u + 0x7FFFu + ((u >> 16) & 1u);
  return (unsigned short)(u >> 16);
}
__device__ __forceinline__ float sigmoidf_(float x){ return 1.0f/(1.0f + __expf(-x)); }
__device__ __forceinline__ float tanhf_(float x){ float e = __expf(2.0f*x); return (e-1.0f)/(e+1.0f); }

// fp32-accumulating L1 step on packed fp16 pairs: acc += |a-b|.x + |a-b|.y  (v_dot2_f32_f16)
__device__ __forceinline__ float l1d(float acc, unsigned int ua, unsigned int ub){
  __half2 a = __builtin_bit_cast(__half2, ua);
  __half2 b = __builtin_bit_cast(__half2, ub);
  __half2 d = __habs2(__hsub2(a, b));
  h2v dv = __builtin_bit_cast(h2v, d);
  h2v ones; ones[0] = (_Float16)1.0f; ones[1] = (_Float16)1.0f;
  return __builtin_amdgcn_fdot2(dv, ones, acc, false);
}
__device__ __forceinline__ float l1d4(float acc, uint4 a, uint4 b){
  acc = l1d(acc, a.x, b.x); acc = l1d(acc, a.y, b.y);
  acc = l1d(acc, a.z, b.z); acc = l1d(acc, a.w, b.w);
  return acc;
}

// ---------------- prep: Tm -> bf16 MFMA-fragment order  +  weight transposes ----------------
// tmh[b] layout: element ((chunk)*96 + c)*8 + h  holds bf16(Tm[k=chunk*8+h][b][c])
__global__ void k_prep(const float* __restrict__ Tm, unsigned short* __restrict__ tmh,
                       const float* __restrict__ wih0, const float* __restrict__ whh0,
                       const float* __restrict__ wih1, const float* __restrict__ whh1,
                       const float* __restrict__ w1,
                       float* __restrict__ wih0T, float* __restrict__ whh0T,
                       float* __restrict__ wih1T, float* __restrict__ whh1T,
                       float* __restrict__ wfcT){
  if (blockIdx.x < 128){
    int b = blockIdx.x;
    for (int e = threadIdx.x; e < HID*CDIM; e += 256){
      int chunk = e / 768;
      int r1 = e - chunk*768;
      int c = r1 >> 3, h = r1 & 7;
      int k = chunk*8 + h;
      tmh[b*(HID*CDIM) + e] = f2bf(Tm[k*(HID*CDIM) + b*CDIM + c]);
    }
  } else {
    int mb = blockIdx.x - 128;   // 0..23
    const float* srcs[5] = {wih0, whh0, wih1, whh1, w1};
    float*       dsts[5] = {wih0T, whh0T, wih1T, whh1T, wfcT};
    const int Rs[5] = {384,384,384,384,128};
    const int Ks[5] = {64,128,128,128,160};
    for (int mm = 0; mm < 5; mm++){
      const float* s = srcs[mm]; float* d = dsts[mm];
      int R = Rs[mm], K = Ks[mm], tot = R*K;
      for (int e = mb*256 + (int)threadIdx.x; e < tot; e += 24*256){
        int r = e / K, k = e - r*K;
        d[k*R + r] = s[e];
      }
    }
  }
}

// ---------------- projection GEMM ----------------
// FUSE=true additionally emits relu'd bf16 in MFMA A-fragment order:
//   pos = t*8192 + (n>>4)*2048 + (j>>3)*128 + (n&15)*8 + (j&7)
template<int K1, int K2, int R, bool FUSE>
__global__ __launch_bounds__(256) void k_proj(const float* __restrict__ in1, const float* __restrict__ in2,
                                              const float* __restrict__ wT, const float* __restrict__ bias,
                                              float* __restrict__ outf, unsigned short* __restrict__ outh){
  constexpr int K = K1 + K2;
  constexpr int KH = K/2;
  __shared__ float xs[32*K];
  __shared__ float part[32*128];
  int tid = threadIdx.x;
  int tn0 = blockIdx.x*32;
  int rb  = blockIdx.y*128;
  int w = tid >> 6, lane = tid & 63;
  int rt = w >> 1, kh = w & 1;
  int r = rb + rt*64 + lane;
  float wreg[KH];
  #pragma unroll
  for (int i = 0; i < KH; i++) wreg[i] = wT[(kh*KH + i)*R + r];
  const float4* i1 = (const float4*)(in1 + tn0*K1);
  for (int g = tid; g < 32*(K1/4); g += 256){
    int tnl = g / (K1/4), k4 = g - tnl*(K1/4);
    *(float4*)&xs[tnl*K + k4*4] = i1[g];
  }
  if (K2 > 0){
    const float4* i2 = (const float4*)(in2 + tn0*K2);
    for (int g = tid; g < 32*(K2/4); g += 256){
      int tnl = g / (K2/4), k4 = g - tnl*(K2/4);
      *(float4*)&xs[tnl*K + K1 + k4*4] = i2[g];
    }
  }
  __syncthreads();
  float acc[32];
  #pragma unroll
  for (int i = 0; i < 32; i++) acc[i] = 0.0f;
  #pragma unroll
  for (int kc = 0; kc < KH/4; kc++){
    #pragma unroll
    for (int tnl = 0; tnl < 32; tnl++){
      float4 xv = *(const float4*)&xs[tnl*K + kh*KH + kc*4];
      acc[tnl] += wreg[kc*4]*xv.x + wreg[kc*4+1]*xv.y + wreg[kc*4+2]*xv.z + wreg[kc*4+3]*xv.w;
    }
  }
  if (kh == 1){
    #pragma unroll
    for (int tnl = 0; tnl < 32; tnl++) part[tnl*128 + rt*64 + lane] = acc[tnl];
  }
  __syncthreads();
  if (kh == 0){
    float bv = bias[r];
    #pragma unroll
    for (int tnl = 0; tnl < 32; tnl++){
      float v = acc[tnl] + part[tnl*128 + rt*64 + lane] + bv;
      if (FUSE) v = fmaxf(v, 0.0f);
      int tn = tn0 + tnl;
      outf[tn*R + r] = v;
      if (FUSE){
        int t = tn >> 6, n = tn & 63, j = r;
        outh[t*8192 + (n>>4)*2048 + (j>>3)*128 + (n&15)*8 + (j&7)] = f2bf(v);
      }
    }
  }
}

// ---------------- GRU recurrence: one block per sample, recurrent weights in VGPRs ----------------
__global__ __launch_bounds__(768) void k_gru(const float* __restrict__ gi, const float* __restrict__ whhT,
                                             const float* __restrict__ bhh, float* __restrict__ hout){
  __shared__ __align__(16) float hl[HID];
  __shared__ float ghl[G3];
  int n = blockIdx.x, tid = threadIdx.x;
  int r = tid >> 1, kh = tid & 1;
  float wreg[64];
  #pragma unroll
  for (int i = 0; i < 64; i++) wreg[i] = whhT[(kh*64 + i)*G3 + r];
  float bias = (kh == 0) ? bhh[r] : 0.0f;
  if (tid < HID) hl[tid] = 0.0f;
  float g_r = 0.0f, g_z = 0.0f, g_n = 0.0f;
  if (tid < HID){
    const float* g0 = gi + n*G3 + tid;
    g_r = g0[0]; g_z = g0[HID]; g_n = g0[2*HID];
  }
  __syncthreads();
  for (int t = 0; t < T_STEPS; t++){
    float acc[4];
    acc[0] = bias; acc[1] = 0.0f; acc[2] = 0.0f; acc[3] = 0.0f;
    #pragma unroll
    for (int i16 = 0; i16 < 16; i16++){
      float4 h4 = *(const float4*)&hl[kh*64 + i16*4];   // broadcast read
      acc[i16 & 3] += wreg[i16*4]*h4.x + wreg[i16*4+1]*h4.y + wreg[i16*4+2]*h4.z + wreg[i16*4+3]*h4.w;
    }
    float at = (acc[0] + acc[1]) + (acc[2] + acc[3]);
    float asum = at + __shfl_xor(at, 1);
    if (kh == 0) ghl[r] = asum;
    __syncthreads();
    if (tid < HID){
      float cr = g_r, cz = g_z, cn = g_n;
      int tnext = (t+1 < T_STEPS) ? t+1 : t;           // prefetch next timestep's gi
      const float* gp = gi + (tnext*NB + n)*G3 + tid;
      g_r = gp[0]; g_z = gp[HID]; g_n = gp[2*HID];
      float rg = sigmoidf_(cr + ghl[tid]);
      float z  = sigmoidf_(cz + ghl[tid+HID]);
      float nn = tanhf_   (cn + rg*ghl[tid+2*HID]);
      float hn = (1.0f - z)*nn + z*hl[tid];
      hl[tid] = hn;
      hout[(t*NB + n)*HID + tid] = hn;
    }
    __syncthreads();
  }
}

// ---------------- minibatch discrimination: one block per (b,t) ----------------
// MFMA with A/B fragments straight from global (fragment-ordered, L1-resident) -> M fp16 in LDS
// -> symmetric tournament pairwise with fp32 fdot2 accumulation -> ps[][] tree reduce (no atomics).
__global__ __launch_bounds__(256) void k_disc(const unsigned short* __restrict__ fc1h,
                                              const unsigned short* __restrict__ tmh,
                                              float* __restrict__ O){
  __shared__ __align__(16) __half Mh[64*104];   // stored row = (rr*16 + wave*4 + quad) -> col[]-index = actual n
  __shared__ float ps[64*18];
  int b = blockIdx.x, t = blockIdx.y;
  int tid = threadIdx.x;
  int wave = tid >> 6, lane = tid & 63, m = lane & 15, quad = lane >> 4;
  // ---- MFMA phase: A,B frags from global ----
  const uint4* Ag = (const uint4*)(fc1h + t*8192);
  const uint4* Bg = (const uint4*)(tmh + b*(CDIM*HID));
  uint4 a4[4];
  #pragma unroll
  for (int kk = 0; kk < 4; kk++) a4[kk] = Ag[wave*256 + (kk*4 + quad)*16 + m];
  f32x4 acc[6];
  #pragma unroll
  for (int i = 0; i < 6; i++) acc[i] = (f32x4)(0.0f);
  #pragma unroll
  for (int kk = 0; kk < 4; kk++){
    short8 av = __builtin_bit_cast(short8, a4[kk]);
    #pragma unroll
    for (int nt = 0; nt < 6; nt++){
      uint4 b4 = Bg[(kk*4 + quad)*96 + nt*16 + m];
      acc[nt] = __builtin_amdgcn_mfma_f32_16x16x32_bf16(av, __builtin_bit_cast(short8, b4), acc[nt], 0, 0, 0);
    }
  }
  #pragma unroll
  for (int nt = 0; nt < 6; nt++){
    #pragma unroll
    for (int rr = 0; rr < 4; rr++){
      Mh[(rr*16 + wave*4 + quad)*104 + nt*16 + m] = __float2half(acc[nt][rr]);
    }
  }
  __syncthreads();
  const uint4* M4 = (const uint4*)Mh;   // 13 uint4 per row, 12 valid
  if (tid < 240){
    // off-diagonal tile pairs: 120 pairs (circle method) x 2 c-halves
    int chalf = tid & 1, tp = tid >> 1;
    int rnd = tp >> 3, slot = tp & 7;
    int ta, tb;
    if (slot == 0){ ta = 15; tb = rnd; }
    else {
      ta = rnd + slot;      if (ta >= 15) ta -= 15;
      tb = rnd + 15 - slot; if (tb >= 15) tb -= 15;
    }
    float facc[16];
    #pragma unroll
    for (int p = 0; p < 16; p++) facc[p] = 0.0f;
    #pragma unroll
    for (int c = 0; c < 6; c++){
      int ch = chalf*6 + c;
      uint4 av[4], bv[4];
      #pragma unroll
      for (int s = 0; s < 4; s++){
        av[s] = M4[(s*16 + ta)*13 + ch];
        bv[s] = M4[(s*16 + tb)*13 + ch];
      }
      #pragma unroll
      for (int i = 0; i < 4; i++)
        #pragma unroll
        for (int j = 0; j < 4; j++)
          facc[i*4+j] = l1d4(facc[i*4+j], av[i], bv[j]);
    }
    float tot[16];
    #pragma unroll
    for (int p = 0; p < 16; p++) tot[p] = facc[p] + __shfl_xor(facc[p], 1);
    if (chalf == 0){
      #pragma unroll
      for (int i = 0; i < 4; i++){
        float s = 0.0f;
        #pragma unroll
        for (int j = 0; j < 4; j++) s += __expf(-tot[i*4+j]);
        ps[(ta*4 + i)*18 + tb] = s;
      }
    } else {
      #pragma unroll
      for (int j = 0; j < 4; j++){
        float s = 0.0f;
        #pragma unroll
        for (int i = 0; i < 4; i++) s += __expf(-tot[i*4+j]);
        ps[(tb*4 + j)*18 + ta] = s;
      }
    }
  } else {
    // self tiles: 16 threads, 6 intra-pairs each, full c range
    int ta = tid - 240;
    float f6[6];
    #pragma unroll
    for (int p = 0; p < 6; p++) f6[p] = 0.0f;
    for (int ch = 0; ch < 12; ch++){
      uint4 rv[4];
      #pragma unroll
      for (int s = 0; s < 4; s++) rv[s] = M4[(s*16 + ta)*13 + ch];
      f6[0] = l1d4(f6[0], rv[0], rv[1]);
      f6[1] = l1d4(f6[1], rv[0], rv[2]);
      f6[2] = l1d4(f6[2], rv[0], rv[3]);
      f6[3] = l1d4(f6[3], rv[1], rv[2]);
      f6[4] = l1d4(f6[4], rv[1], rv[3]);
      f6[5] = l1d4(f6[5], rv[2], rv[3]);
    }
    float e01 = __expf(-f6[0]), e02 = __expf(-f6[1]), e03 = __expf(-f6[2]);
    float e12 = __expf(-f6[3]), e13 = __expf(-f6[4]), e23 = __expf(-f6[5]);
    ps[(ta*4 + 0)*18 + ta] = e01 + e02 + e03;
    ps[(ta*4 + 1)*18 + ta] = e01 + e12 + e13;
    ps[(ta*4 + 2)*18 + ta] = e02 + e12 + e23;
    ps[(ta*4 + 3)*18 + ta] = e03 + e13 + e23;
  }
  __syncthreads();
  if (tid < NB){
    float s = 0.0f;
    #pragma unroll
    for (int k = 0; k < 16; k++) s += ps[tid*18 + k];
    O[(t*HID + b)*NB + tid] = s*(1.0f/63.0f);
  }
}

// ---------------- final ----------------
__global__ __launch_bounds__(256) void k_final(const float* __restrict__ fc1f, const float* __restrict__ O,
                                               const float* __restrict__ w2, const float* __restrict__ b2,
                                               float* __restrict__ out){
  __shared__ float ol[NB*HID];      // [b][n]
  __shared__ float fl[NB*130];
  __shared__ float wl[2*HID + 2];
  int t = blockIdx.x, tid = threadIdx.x;
  for (int i = tid; i < NB*HID; i += 256) ol[i] = O[t*NB*HID + i];
  for (int i = tid; i < NB*HID; i += 256){ int n = i >> 7, h = i & 127; fl[n*130 + h] = fc1f[t*NB*HID + i]; }
  if (tid < 2*HID) wl[tid] = w2[tid];
  if (tid == 0) wl[2*HID] = b2[0];
  __syncthreads();
  if (tid < NB){
    float acc = wl[2*HID];
    #pragma unroll 8
    for (int h = 0; h < HID; h++) acc += fl[tid*130 + h]*wl[h];
    #pragma unroll 8
    for (int b = 0; b < HID; b++) acc += ol[b*NB + tid]*wl[HID + b];
    out[t*NB + tid] = sigmoidf_(acc);
  }
}

extern "C" void kernel_launch(void* const* d_in, const int* in_sizes, int n_in,
                              void* d_out, int out_size, void* d_ws, size_t ws_size,
                              hipStream_t stream){
  const float* x    = (const float*)d_in[0];
  const float* a    = (const float*)d_in[1];
  const float* wih0 = (const float*)d_in[2];
  const float* whh0 = (const float*)d_in[3];
  const float* bih0 = (const float*)d_in[4];
  const float* bhh0 = (const float*)d_in[5];
  const float* wih1 = (const float*)d_in[6];
  const float* whh1 = (const float*)d_in[7];
  const float* bih1 = (const float*)d_in[8];
  const float* bhh1 = (const float*)d_in[9];
  const float* w1   = (const float*)d_in[10];
  const float* b1   = (const float*)d_in[11];
  const float* w2   = (const float*)d_in[12];
  const float* b2   = (const float*)d_in[13];
  const float* Tm   = (const float*)d_in[14];
  float* ws = (float*)d_ws;
  float* gi    = ws;                    // 786432
  float* hs0   = ws + 786432;           // 262144
  float* hs1   = ws + 1048576;          // 262144
  float* fc1f  = ws + 1310720;          // 262144
  float* Ows   = ws + 1572864;          // 262144
  unsigned short* fc1h = (unsigned short*)(ws + 1835008);  // 262144 halves (frag order)
  unsigned short* tmh  = (unsigned short*)(ws + 1966080);  // 1572864 halves (frag order)
  float* wih0T = ws + 2752512;
  float* whh0T = ws + 2777088;
  float* wih1T = ws + 2826240;
  float* whh1T = ws + 2875392;
  float* wfcT  = ws + 2924544;
  float* out = (float*)d_out;

  k_prep<<<dim3(152), dim3(256), 0, stream>>>(Tm, tmh, wih0, whh0, wih1, whh1, w1,
                                              wih0T, whh0T, wih1T, whh1T, wfcT);
  k_proj<64, 0, 384, false><<<dim3(64, 3), dim3(256), 0, stream>>>(x, nullptr, wih0T, bih0, gi, nullptr);
  k_gru<<<dim3(NB), dim3(768), 0, stream>>>(gi, whh0T, bhh0, hs0);
  k_proj<128, 0, 384, false><<<dim3(64, 3), dim3(256), 0, stream>>>(hs0, nullptr, wih1T, bih1, gi, nullptr);
  k_gru<<<dim3(NB), dim3(768), 0, stream>>>(gi, whh1T, bhh1, hs1);
  k_proj<128, 32, 128, true><<<dim3(64, 1), dim3(256), 0, stream>>>(hs1, a, wfcT, b1, fc1f, fc1h);
  k_disc<<<dim3(HID, T_STEPS), dim3(256), 0, stream>>>(fc1h, tmh, Ows);
  k_final<<<dim3(T_STEPS), dim3(256), 0, stream>>>(fc1f, Ows, w2, b2, out);
}

// Round 4
// 212.833 us; speedup vs baseline: 2.1860x; 1.3675x over previous
//
#include <hip/hip_runtime.h>
#include <hip/hip_fp16.h>
#include <cstdint>

#define T_STEPS 32
#define NB 64
#define STATE 64
#define HID 128
#define ACT 32
#define CDIM 96
#define G3 (3*HID)   // 384

typedef __attribute__((ext_vector_type(8))) short short8;
typedef __attribute__((ext_vector_type(4))) float f32x4;
typedef _Float16 h2v __attribute__((ext_vector_type(2)));

__device__ __forceinline__ unsigned short f2bf(float f){
  unsigned int u = __builtin_bit_cast(unsigned int, f);
  u = u + 0x7FFFu + ((u >> 16) & 1u);
  return (unsigned short)(u >> 16);
}
__device__ __forceinline__ unsigned int packh2(float f0, float f1){
  return (unsigned int)__half_as_ushort(__float2half_rn(f0)) |
         ((unsigned int)__half_as_ushort(__float2half_rn(f1)) << 16);
}
__device__ __forceinline__ float sigmoidf_(float x){ return 1.0f/(1.0f + __expf(-x)); }
__device__ __forceinline__ float tanhf_(float x){ float e = __expf(2.0f*x); return (e-1.0f)/(e+1.0f); }

// fp32-accumulating packed-fp16 dot: acc += a.x*b.x + a.y*b.y
__device__ __forceinline__ float dot2f(float acc, unsigned int a, unsigned int b){
  h2v av = __builtin_bit_cast(h2v, a);
  h2v bv = __builtin_bit_cast(h2v, b);
  return __builtin_amdgcn_fdot2(av, bv, acc, false);
}
// L1 step: acc += |a-b|.x + |a-b|.y
__device__ __forceinline__ float l1d(float acc, unsigned int ua, unsigned int ub){
  __half2 a = __builtin_bit_cast(__half2, ua);
  __half2 b = __builtin_bit_cast(__half2, ub);
  __half2 d = __habs2(__hsub2(a, b));
  h2v dv = __builtin_bit_cast(h2v, d);
  h2v ones; ones[0] = (_Float16)1.0f; ones[1] = (_Float16)1.0f;
  return __builtin_amdgcn_fdot2(dv, ones, acc, false);
}
__device__ __forceinline__ float l1d4(float acc, uint4 a, uint4 b){
  acc = l1d(acc, a.x, b.x); acc = l1d(acc, a.y, b.y);
  acc = l1d(acc, a.z, b.z); acc = l1d(acc, a.w, b.w);
  return acc;
}

// ---------------- prep: Tm -> bf16 MFMA B-frag order + fp16-packed GRU/fc weights ----------------
__global__ void k_prep(const float* __restrict__ Tm, unsigned short* __restrict__ tmh,
                       const float* __restrict__ wih0, const float* __restrict__ whh0,
                       const float* __restrict__ wih1, const float* __restrict__ whh1,
                       const float* __restrict__ w1,
                       unsigned int* __restrict__ wih0p, unsigned int* __restrict__ whh0p,
                       unsigned int* __restrict__ wih1p, unsigned int* __restrict__ whh1p,
                       unsigned int* __restrict__ w1p){
  int tid = threadIdx.x;
  if (blockIdx.x < 128){
    int b = blockIdx.x;
    for (int e = tid; e < HID*CDIM; e += 256){
      int chunk = e / 768;
      int r1 = e - chunk*768;
      int c = r1 >> 3, h = r1 & 7;
      int k = chunk*8 + h;
      tmh[b*(HID*CDIM) + e] = f2bf(Tm[k*(HID*CDIM) + b*CDIM + c]);
    }
  } else {
    int mb = blockIdx.x - 128;   // 0..7
    const float* srcs[5] = {wih0, whh0, wih1, whh1, w1};
    unsigned int* dsts[5] = {wih0p, whh0p, wih1p, whh1p, w1p};
    const int Rs[5]  = {384,384,384,384,128};
    const int K2s[5] = {32,64,64,64,80};
    for (int mm = 0; mm < 5; mm++){
      const float* s = srcs[mm]; unsigned int* d = dsts[mm];
      int R = Rs[mm], K2 = K2s[mm], tot = R*K2;
      for (int e = mb*256 + tid; e < tot; e += 8*256){
        int k2 = e / R, r = e - k2*R;
        d[e] = packh2(s[r*(2*K2) + 2*k2], s[r*(2*K2) + 2*k2 + 1]);
      }
    }
  }
}

// ---------------- GRU layer 0: fused x-projection + recurrence + layer-1 input projection ----------------
// thread = (r = tid>>1, kh = tid&1); weights fp16-packed in VGPRs; h fp16 in LDS (broadcast reads).
__global__ __launch_bounds__(768) void k_gru0(const float* __restrict__ x,
                                              const unsigned int* __restrict__ wih0p,
                                              const unsigned int* __restrict__ whh0p,
                                              const unsigned int* __restrict__ wih1p,
                                              const float* __restrict__ bih0, const float* __restrict__ bhh0,
                                              const float* __restrict__ bih1,
                                              float* __restrict__ gi1g){
  __shared__ __align__(16) unsigned int hl2[64];     // h as 64 h2 (128 fp16)
  __shared__ __align__(16) unsigned int xall[1024];  // all x[t,n,:] fp16: [t][32 h2]
  __shared__ float ghl[G3], gil[G3];
  int n = blockIdx.x, tid = threadIdx.x;
  int r = tid >> 1, kh = tid & 1;
  unsigned int wi0[16], wh0[32], wi1[32];
  #pragma unroll
  for (int i = 0; i < 16; i++) wi0[i] = wih0p[(kh*16 + i)*384 + r];
  #pragma unroll
  for (int i = 0; i < 32; i++) wh0[i] = whh0p[(kh*32 + i)*384 + r];
  #pragma unroll
  for (int i = 0; i < 32; i++) wi1[i] = wih1p[(kh*32 + i)*384 + r];
  float bh0 = (kh == 0) ? bhh0[r] : 0.0f;
  float bi0 = (kh == 0) ? bih0[r] : 0.0f;
  float bi1 = (kh == 0) ? bih1[r] : 0.0f;
  for (int e = tid; e < 1024; e += 768){
    int t_ = e >> 5, i = e & 31;
    const float* xp = x + t_*(NB*STATE) + n*STATE + 2*i;
    xall[e] = packh2(xp[0], xp[1]);
  }
  if (tid < 64) hl2[tid] = 0u;
  float hprev = 0.0f;
  __syncthreads();
  const uint4* hl4 = (const uint4*)hl2;
  for (int t = 0; t <= T_STEPS; t++){
    float gh = bh0, gi1 = bi1, gi0 = bi0;
    #pragma unroll
    for (int g = 0; g < 2; g++){
      uint4 hv[4];
      #pragma unroll
      for (int j = 0; j < 4; j++) hv[j] = hl4[kh*8 + g*4 + j];
      #pragma unroll
      for (int j = 0; j < 4; j++){
        gh = dot2f(gh, wh0[g*16 + j*4 + 0], hv[j].x);
        gh = dot2f(gh, wh0[g*16 + j*4 + 1], hv[j].y);
        gh = dot2f(gh, wh0[g*16 + j*4 + 2], hv[j].z);
        gh = dot2f(gh, wh0[g*16 + j*4 + 3], hv[j].w);
        gi1 = dot2f(gi1, wi1[g*16 + j*4 + 0], hv[j].x);
        gi1 = dot2f(gi1, wi1[g*16 + j*4 + 1], hv[j].y);
        gi1 = dot2f(gi1, wi1[g*16 + j*4 + 2], hv[j].z);
        gi1 = dot2f(gi1, wi1[g*16 + j*4 + 3], hv[j].w);
      }
    }
    if (t < T_STEPS){
      const uint4* xl4 = (const uint4*)&xall[t*32];
      #pragma unroll
      for (int j = 0; j < 4; j++){
        uint4 xv = xl4[kh*4 + j];
        gi0 = dot2f(gi0, wi0[j*4 + 0], xv.x);
        gi0 = dot2f(gi0, wi0[j*4 + 1], xv.y);
        gi0 = dot2f(gi0, wi0[j*4 + 2], xv.z);
        gi0 = dot2f(gi0, wi0[j*4 + 3], xv.w);
      }
    }
    gh  += __shfl_xor(gh, 1);
    gi1 += __shfl_xor(gi1, 1);
    gi0 += __shfl_xor(gi0, 1);
    if (kh == 0){
      if (t < T_STEPS){ ghl[r] = gh; gil[r] = gi0; }
      if (t >= 1) gi1g[((t-1)*NB + n)*G3 + r] = gi1;
    }
    __syncthreads();
    if (t < T_STEPS && tid < HID){
      float rg = sigmoidf_(gil[tid]       + ghl[tid]);
      float z  = sigmoidf_(gil[tid+HID]   + ghl[tid+HID]);
      float nn = tanhf_   (gil[tid+2*HID] + rg*ghl[tid+2*HID]);
      float hn = (1.0f - z)*nn + z*hprev;
      hprev = hn;
      ((__half*)hl2)[tid] = __float2half_rn(hn);
    }
    __syncthreads();
  }
}

// ---------------- GRU layer 1: recurrence + fused fc1 (relu + bf16-frag emission) ----------------
__global__ __launch_bounds__(768) void k_gru1(const float* __restrict__ a,
                                              const unsigned int* __restrict__ whh1p,
                                              const unsigned int* __restrict__ w1p,
                                              const float* __restrict__ bhh1, const float* __restrict__ b1,
                                              const float* __restrict__ gi1g,
                                              float* __restrict__ fc1f, unsigned short* __restrict__ fc1h){
  __shared__ __align__(16) unsigned int hl2[64];
  __shared__ __align__(16) unsigned int aall[512];   // all a[t,n,:] fp16: [t][16 h2]
  __shared__ float ghl[G3];
  int n = blockIdx.x, tid = threadIdx.x;
  int r = tid >> 1, kh = tid & 1;
  unsigned int wh1[32];
  #pragma unroll
  for (int i = 0; i < 32; i++) wh1[i] = whh1p[(kh*32 + i)*384 + r];
  unsigned int w1h[32], w1a[8];
  if (r < HID){
    #pragma unroll
    for (int i = 0; i < 32; i++) w1h[i] = w1p[(kh*32 + i)*128 + r];
    #pragma unroll
    for (int i = 0; i < 8; i++)  w1a[i] = w1p[(64 + kh*8 + i)*128 + r];
  }
  float bh1 = (kh == 0) ? bhh1[r] : 0.0f;
  float bf1 = (kh == 0 && r < HID) ? b1[r] : 0.0f;
  for (int e = tid; e < 512; e += 768){
    int t_ = e >> 4, i = e & 15;
    const float* ap = a + t_*(NB*ACT) + n*ACT + 2*i;
    aall[e] = packh2(ap[0], ap[1]);
  }
  if (tid < 64) hl2[tid] = 0u;
  float hprev = 0.0f;
  float g_r = 0.0f, g_z = 0.0f, g_n = 0.0f;
  if (tid < HID){
    const float* gp = gi1g + n*G3 + tid;
    g_r = gp[0]; g_z = gp[HID]; g_n = gp[2*HID];
  }
  __syncthreads();
  const uint4* hl4 = (const uint4*)hl2;
  for (int t = 0; t <= T_STEPS; t++){
    float gh = bh1, fc = bf1;
    bool dofc = (r < HID) && (t >= 1);
    #pragma unroll
    for (int g = 0; g < 2; g++){
      uint4 hv[4];
      #pragma unroll
      for (int j = 0; j < 4; j++) hv[j] = hl4[kh*8 + g*4 + j];
      #pragma unroll
      for (int j = 0; j < 4; j++){
        gh = dot2f(gh, wh1[g*16 + j*4 + 0], hv[j].x);
        gh = dot2f(gh, wh1[g*16 + j*4 + 1], hv[j].y);
        gh = dot2f(gh, wh1[g*16 + j*4 + 2], hv[j].z);
        gh = dot2f(gh, wh1[g*16 + j*4 + 3], hv[j].w);
      }
      if (dofc){
        #pragma unroll
        for (int j = 0; j < 4; j++){
          fc = dot2f(fc, w1h[g*16 + j*4 + 0], hv[j].x);
          fc = dot2f(fc, w1h[g*16 + j*4 + 1], hv[j].y);
          fc = dot2f(fc, w1h[g*16 + j*4 + 2], hv[j].z);
          fc = dot2f(fc, w1h[g*16 + j*4 + 3], hv[j].w);
        }
      }
    }
    if (dofc){
      const uint4* al4 = (const uint4*)&aall[(t-1)*16];
      #pragma unroll
      for (int j = 0; j < 2; j++){
        uint4 av = al4[kh*2 + j];
        fc = dot2f(fc, w1a[j*4 + 0], av.x);
        fc = dot2f(fc, w1a[j*4 + 1], av.y);
        fc = dot2f(fc, w1a[j*4 + 2], av.z);
        fc = dot2f(fc, w1a[j*4 + 3], av.w);
      }
    }
    gh += __shfl_xor(gh, 1);
    fc += __shfl_xor(fc, 1);
    if (kh == 0){
      if (t < T_STEPS) ghl[r] = gh;
      if (t >= 1 && r < HID){
        float v = fmaxf(fc, 0.0f);
        fc1f[((t-1)*NB + n)*HID + r] = v;
        fc1h[(t-1)*8192 + (n>>4)*2048 + (r>>3)*128 + (n&15)*8 + (r&7)] = f2bf(v);
      }
    }
    __syncthreads();
    if (t < T_STEPS && tid < HID){
      float cr = g_r, cz = g_z, cn = g_n;
      int tn2 = (t+1 < T_STEPS) ? t+1 : t;
      const float* gp = gi1g + (tn2*NB + n)*G3 + tid;
      g_r = gp[0]; g_z = gp[HID]; g_n = gp[2*HID];
      float rg = sigmoidf_(cr + ghl[tid]);
      float z  = sigmoidf_(cz + ghl[tid+HID]);
      float nn = tanhf_   (cn + rg*ghl[tid+2*HID]);
      float hn = (1.0f - z)*nn + z*hprev;
      hprev = hn;
      ((__half*)hl2)[tid] = __float2half_rn(hn);
    }
    __syncthreads();
  }
}

// ---------------- minibatch discrimination: one block per (b,t) ----------------
// MFMA frags from global -> M fp16 in LDS -> symmetric tournament pairwise with
// monotone early-exit (L1 partial > 14 => exp contribution < 8e-7, provably negligible).
__global__ __launch_bounds__(256) void k_disc(const unsigned short* __restrict__ fc1h,
                                              const unsigned short* __restrict__ tmh,
                                              float* __restrict__ O){
  __shared__ __align__(16) __half Mh[64*104];
  __shared__ float ps[64*18];
  int b = blockIdx.x, t = blockIdx.y;
  int tid = threadIdx.x;
  int wave = tid >> 6, lane = tid & 63, m = lane & 15, quad = lane >> 4;
  const uint4* Ag = (const uint4*)(fc1h + t*8192);
  const uint4* Bg = (const uint4*)(tmh + b*(CDIM*HID));
  uint4 a4[4];
  #pragma unroll
  for (int kk = 0; kk < 4; kk++) a4[kk] = Ag[wave*256 + (kk*4 + quad)*16 + m];
  f32x4 acc[6];
  #pragma unroll
  for (int i = 0; i < 6; i++) acc[i] = (f32x4)(0.0f);
  #pragma unroll
  for (int kk = 0; kk < 4; kk++){
    short8 av = __builtin_bit_cast(short8, a4[kk]);
    #pragma unroll
    for (int nt = 0; nt < 6; nt++){
      uint4 b4 = Bg[(kk*4 + quad)*96 + nt*16 + m];
      acc[nt] = __builtin_amdgcn_mfma_f32_16x16x32_bf16(av, __builtin_bit_cast(short8, b4), acc[nt], 0, 0, 0);
    }
  }
  #pragma unroll
  for (int nt = 0; nt < 6; nt++){
    #pragma unroll
    for (int rr = 0; rr < 4; rr++){
      Mh[(rr*16 + wave*4 + quad)*104 + nt*16 + m] = __float2half(acc[nt][rr]);
    }
  }
  __syncthreads();
  const uint4* M4 = (const uint4*)Mh;   // 13 uint4 per row, 12 valid
  if (tid < 240){
    int chalf = tid & 1, tp = tid >> 1;
    int rnd = tp >> 3, slot = tp & 7;
    int ta, tb;
    if (slot == 0){ ta = 15; tb = rnd; }
    else {
      ta = rnd + slot;      if (ta >= 15) ta -= 15;
      tb = rnd + 15 - slot; if (tb >= 15) tb -= 15;
    }
    float facc[16];
    #pragma unroll
    for (int p = 0; p < 16; p++) facc[p] = 0.0f;
    auto doChunk = [&](int c){
      int ch = chalf*6 + c;
      uint4 av[4], bv[4];
      #pragma unroll
      for (int s = 0; s < 4; s++){
        av[s] = M4[(s*16 + ta)*13 + ch];
        bv[s] = M4[(s*16 + tb)*13 + ch];
      }
      #pragma unroll
      for (int i = 0; i < 4; i++)
        #pragma unroll
        for (int j = 0; j < 4; j++)
          facc[i*4+j] = l1d4(facc[i*4+j], av[i], bv[j]);
    };
    doChunk(0); doChunk(1);
    bool big1 = true;
    #pragma unroll
    for (int p = 0; p < 16; p++) big1 = big1 && (facc[p] > 14.0f);
    if (!big1){
      doChunk(2); doChunk(3);
      bool big2 = true;
      #pragma unroll
      for (int p = 0; p < 16; p++) big2 = big2 && (facc[p] > 14.0f);
      if (!big2){ doChunk(4); doChunk(5); }
    }
    float tot[16];
    #pragma unroll
    for (int p = 0; p < 16; p++) tot[p] = facc[p] + __shfl_xor(facc[p], 1);
    if (chalf == 0){
      #pragma unroll
      for (int i = 0; i < 4; i++){
        float s = 0.0f;
        #pragma unroll
        for (int j = 0; j < 4; j++) s += __expf(-tot[i*4+j]);
        ps[(ta*4 + i)*18 + tb] = s;
      }
    } else {
      #pragma unroll
      for (int j = 0; j < 4; j++){
        float s = 0.0f;
        #pragma unroll
        for (int i = 0; i < 4; i++) s += __expf(-tot[i*4+j]);
        ps[(tb*4 + j)*18 + ta] = s;
      }
    }
  } else {
    int ta = tid - 240;
    float f6[6];
    #pragma unroll
    for (int p = 0; p < 6; p++) f6[p] = 0.0f;
    auto doChunkS = [&](int ch){
      uint4 rv[4];
      #pragma unroll
      for (int s = 0; s < 4; s++) rv[s] = M4[(s*16 + ta)*13 + ch];
      f6[0] = l1d4(f6[0], rv[0], rv[1]);
      f6[1] = l1d4(f6[1], rv[0], rv[2]);
      f6[2] = l1d4(f6[2], rv[0], rv[3]);
      f6[3] = l1d4(f6[3], rv[1], rv[2]);
      f6[4] = l1d4(f6[4], rv[1], rv[3]);
      f6[5] = l1d4(f6[5], rv[2], rv[3]);
    };
    doChunkS(0); doChunkS(1); doChunkS(2);
    bool big1 = true;
    #pragma unroll
    for (int p = 0; p < 6; p++) big1 = big1 && (f6[p] > 14.0f);
    if (!big1){
      doChunkS(3); doChunkS(4); doChunkS(5);
      bool big2 = true;
      #pragma unroll
      for (int p = 0; p < 6; p++) big2 = big2 && (f6[p] > 14.0f);
      if (!big2){
        doChunkS(6); doChunkS(7); doChunkS(8);
        doChunkS(9); doChunkS(10); doChunkS(11);
      }
    }
    float e01 = __expf(-f6[0]), e02 = __expf(-f6[1]), e03 = __expf(-f6[2]);
    float e12 = __expf(-f6[3]), e13 = __expf(-f6[4]), e23 = __expf(-f6[5]);
    ps[(ta*4 + 0)*18 + ta] = e01 + e02 + e03;
    ps[(ta*4 + 1)*18 + ta] = e01 + e12 + e13;
    ps[(ta*4 + 2)*18 + ta] = e02 + e12 + e23;
    ps[(ta*4 + 3)*18 + ta] = e03 + e13 + e23;
  }
  __syncthreads();
  if (tid < NB){
    float s = 0.0f;
    #pragma unroll
    for (int k = 0; k < 16; k++) s += ps[tid*18 + k];
    O[(t*HID + b)*NB + tid] = s*(1.0f/63.0f);
  }
}

// ---------------- final ----------------
__global__ __launch_bounds__(256) void k_final(const float* __restrict__ fc1f, const float* __restrict__ O,
                                               const float* __restrict__ w2, const float* __restrict__ b2,
                                               float* __restrict__ out){
  __shared__ float ol[NB*HID];      // [b][n]
  __shared__ float fl[NB*130];
  __shared__ float wl[2*HID + 2];
  int t = blockIdx.x, tid = threadIdx.x;
  for (int i = tid; i < NB*HID; i += 256) ol[i] = O[t*NB*HID + i];
  for (int i = tid; i < NB*HID; i += 256){ int n = i >> 7, h = i & 127; fl[n*130 + h] = fc1f[t*NB*HID + i]; }
  if (tid < 2*HID) wl[tid] = w2[tid];
  if (tid == 0) wl[2*HID] = b2[0];
  __syncthreads();
  if (tid < NB){
    float acc = wl[2*HID];
    #pragma unroll 8
    for (int h = 0; h < HID; h++) acc += fl[tid*130 + h]*wl[h];
    #pragma unroll 8
    for (int b = 0; b < HID; b++) acc += ol[b*NB + tid]*wl[HID + b];
    out[t*NB + tid] = sigmoidf_(acc);
  }
}

extern "C" void kernel_launch(void* const* d_in, const int* in_sizes, int n_in,
                              void* d_out, int out_size, void* d_ws, size_t ws_size,
                              hipStream_t stream){
  const float* x    = (const float*)d_in[0];
  const float* a    = (const float*)d_in[1];
  const float* wih0 = (const float*)d_in[2];
  const float* whh0 = (const float*)d_in[3];
  const float* bih0 = (const float*)d_in[4];
  const float* bhh0 = (const float*)d_in[5];
  const float* wih1 = (const float*)d_in[6];
  const float* whh1 = (const float*)d_in[7];
  const float* bih1 = (const float*)d_in[8];
  const float* bhh1 = (const float*)d_in[9];
  const float* w1   = (const float*)d_in[10];
  const float* b1   = (const float*)d_in[11];
  const float* w2   = (const float*)d_in[12];
  const float* b2   = (const float*)d_in[13];
  const float* Tm   = (const float*)d_in[14];
  float* ws = (float*)d_ws;
  float* gi1g = ws;                                        // 786432 floats
  float* fc1f = ws + 786432;                               // 262144
  float* Ows  = ws + 1048576;                              // 262144
  unsigned short* fc1h = (unsigned short*)(ws + 1310720);  // 262144 ushorts
  unsigned short* tmh  = (unsigned short*)(ws + 1441792);  // 1572864 ushorts
  unsigned int* wih0p = (unsigned int*)(ws + 2228224);     // 12288
  unsigned int* whh0p = (unsigned int*)(ws + 2240512);     // 24576
  unsigned int* wih1p = (unsigned int*)(ws + 2265088);     // 24576
  unsigned int* whh1p = (unsigned int*)(ws + 2289664);     // 24576
  unsigned int* w1p   = (unsigned int*)(ws + 2314240);     // 10240
  float* out = (float*)d_out;

  k_prep<<<dim3(136), dim3(256), 0, stream>>>(Tm, tmh, wih0, whh0, wih1, whh1, w1,
                                              wih0p, whh0p, wih1p, whh1p, w1p);
  k_gru0<<<dim3(NB), dim3(768), 0, stream>>>(x, wih0p, whh0p, wih1p, bih0, bhh0, bih1, gi1g);
  k_gru1<<<dim3(NB), dim3(768), 0, stream>>>(a, whh1p, w1p, bhh1, b1, gi1g, fc1f, fc1h);
  k_disc<<<dim3(HID, T_STEPS), dim3(256), 0, stream>>>(fc1h, tmh, Ows);
  k_final<<<dim3(T_STEPS), dim3(256), 0, stream>>>(fc1f, Ows, w2, b2, out);
}